// Round 3
// baseline (601.476 us; speedup 1.0000x reference)
//
#include <hip/hip_runtime.h>
#include <math.h>

// GCN 2-layer (1->8->1), collapsed + factored + two-level (dst-window x src-block)
// binned so the per-edge gather is an LDS read, not a random global access.
//
// Math (verified):
//   deg[d]  = #edges into d; dinv = rsqrt(deg+1)            (self-loop)
//   v[i]    = dinv[i]*x[i]                                  (stored fp16)
//   acc1[d] = sum_e v[src[e]]
//   at[i]   = dinv[i]*(acc1[i] + v[i])
//   u[i]    = dinv[i] * sum_j relu(at[i]*W1[j]+b1[j])*W2[j] (stored fp16)
//   out[d]  = dinv[d]*(acc2[d] + u[d]) + b2,  acc2[d] = sum_e u[src[e]]
//
// Round-16: r14 (occupancy 33->74%, no gain) + r15 (batched loads, no gain)
// prove the scatter kernels are floored by the random-request path
// (10M random 2B gathers / 70us = 0.56 req/cy/CU; all pipes idle).
// Fix: two-level counting sort by (dst>>12, src>>15) into 7595 groups with
// EXACT sizing (hist+scan prepass; zero slack -> fits 48.8MB known-safe ws).
// gs kernels: one dst-window (4096 nodes, 16KB acc) per block; loop over 31
// src-blocks staging the 64KB v-slice into LDS (double-buffered); per edge:
// ds_read_u16 + LDS atomicAdd. Zero random global requests on the hot path.
// Record = (dstoff12 << 15) | srcoff15 (27 bits).

typedef int vint4 __attribute__((ext_vector_type(4)));

#define DSH    12         // dst-window shift (4096 nodes)
#define DW     4096
#define SSH    15         // src-block shift (32768 nodes)
#define SW     32768
#define NGMAX  8192       // max groups (245*31 = 7595 for N=1e6)
#define CPAD   4          // ints per padded counter (16B anti-contention)
#define SCHUNK 12288      // edges per sort block
#define HCHUNK 32768      // edges per hist block

__device__ __forceinline__ int grp(int d, int s, int NSB) {
    return (int)(((unsigned)d) >> DSH) * NSB + (int)(((unsigned)s) >> SSH);
}
__device__ __forceinline__ int mkrec(int d, int s) {
    return ((d & (DW - 1)) << SSH) | (s & (SW - 1));
}

__global__ void k_zero(int* __restrict__ p, int n) {
    int i = blockIdx.x * blockDim.x + threadIdx.x;
    if (i < n) p[i] = 0;
}

// ---- exact per-group histogram ----
__global__ __launch_bounds__(1024) void k_hist(const int* __restrict__ src,
                                               const int* __restrict__ dst,
                                               int E, int NSB, int NG,
                                               int* __restrict__ cntP) {
    __shared__ int h[NGMAX];
    int t = threadIdx.x;
    for (int i = t; i < NGMAX; i += 1024) h[i] = 0;
    __syncthreads();
    long s0 = (long)blockIdx.x * HCHUNK;
    long rem = (long)E - s0;
    int end = (int)(rem < HCHUNK ? rem : HCHUNK);
    const vint4* pd = reinterpret_cast<const vint4*>(dst + s0);
    const vint4* ps = reinterpret_cast<const vint4*>(src + s0);
    int n4 = end >> 2;
    for (int k = t; k < n4; k += 1024) {
        vint4 d = pd[k], s = ps[k];
        atomicAdd(&h[grp(d.x, s.x, NSB)], 1);
        atomicAdd(&h[grp(d.y, s.y, NSB)], 1);
        atomicAdd(&h[grp(d.z, s.z, NSB)], 1);
        atomicAdd(&h[grp(d.w, s.w, NSB)], 1);
    }
    for (int k = (n4 << 2) + t; k < end; k += 1024)
        atomicAdd(&h[grp(dst[s0 + k], src[s0 + k], NSB)], 1);
    __syncthreads();
    for (int g = t; g < NG; g += 1024) {
        int hv = h[g];
        if (hv) atomicAdd(&cntP[g * CPAD], hv);
    }
}

// ---- exact (4-aligned) prefix offsets; single block ----
__global__ __launch_bounds__(1024) void k_scan(const int* __restrict__ cntP,
                                               int NG, int* __restrict__ scanoff) {
    __shared__ int part[1024];
    int t = threadIdx.x;
    int c[8];
    int sum = 0;
#pragma unroll
    for (int j = 0; j < 8; ++j) {
        int g = t * 8 + j;
        c[j] = (g < NG) ? ((cntP[g * CPAD] + 3) & ~3) : 0;
        sum += c[j];
    }
    part[t] = sum;
    __syncthreads();
    for (int o = 1; o < 1024; o <<= 1) {
        int pv = (t >= o) ? part[t - o] : 0;
        __syncthreads();
        part[t] += pv;
        __syncthreads();
    }
    int run = (t > 0) ? part[t - 1] : 0;
#pragma unroll
    for (int j = 0; j < 8; ++j) {
        int g = t * 8 + j;
        if (g < NG) scanoff[g] = run;
        run += c[j];
    }
}

// ---- two-level counting sort into exact group segments ----
__global__ __launch_bounds__(1024) void k_sort(const int* __restrict__ src,
                                               const int* __restrict__ dst,
                                               int E, int NSB, int NG,
                                               const int* __restrict__ scanoff,
                                               int* __restrict__ gcurP,
                                               int* __restrict__ recs) {
    __shared__ int cnt[NGMAX];            // A: counts; C: cursors
    __shared__ int res[NGMAX];            // res[b] = scanoff[b] + r0 - off[b]
    __shared__ int part[1024];
    __shared__ int stage[SCHUNK];         // 48 KB bucket-ordered staging
    __shared__ unsigned short s2b[SCHUNK];// 24 KB slot -> group

    int t = threadIdx.x;
    for (int i = t; i < NGMAX; i += 1024) cnt[i] = 0;
    __syncthreads();

    long s0 = (long)blockIdx.x * SCHUNK;
    long rem = (long)E - s0;
    int end = (int)(rem < SCHUNK ? rem : SCHUNK);
    const vint4* pd = reinterpret_cast<const vint4*>(dst + s0);
    const vint4* ps = reinterpret_cast<const vint4*>(src + s0);
    int n4 = end >> 2;

    // ---- phase A: group histogram (plain loads: keep lines in L2 for C) ----
    for (int k = t; k < n4; k += 1024) {
        vint4 d = pd[k], s = ps[k];
        atomicAdd(&cnt[grp(d.x, s.x, NSB)], 1);
        atomicAdd(&cnt[grp(d.y, s.y, NSB)], 1);
        atomicAdd(&cnt[grp(d.z, s.z, NSB)], 1);
        atomicAdd(&cnt[grp(d.w, s.w, NSB)], 1);
    }
    for (int k = (n4 << 2) + t; k < end; k += 1024)
        atomicAdd(&cnt[grp(dst[s0 + k], src[s0 + k], NSB)], 1);
    __syncthreads();

    // ---- phase B: 8 groups/thread scan + global reservation ----
    int c[8];
    int sum = 0;
#pragma unroll
    for (int j = 0; j < 8; ++j) { c[j] = cnt[t * 8 + j]; sum += c[j]; }
    part[t] = sum;
    __syncthreads();
    for (int o = 1; o < 1024; o <<= 1) {
        int pv = (t >= o) ? part[t - o] : 0;
        __syncthreads();
        part[t] += pv;
        __syncthreads();
    }
    int run = (t > 0) ? part[t - 1] : 0;
#pragma unroll
    for (int j = 0; j < 8; ++j) {
        int b = t * 8 + j;
        cnt[b] = run;                     // cursor start (block-local)
        if (c[j]) {
            int r0 = atomicAdd(&gcurP[b * CPAD], c[j]);
            res[b] = scanoff[b] + r0 - run;
        }
        run += c[j];
    }
    __syncthreads();

    // ---- phase C: place records into LDS staging (group-ordered) ----
    for (int k = t; k < n4; k += 1024) {
        vint4 d = pd[k], s = ps[k];
        int b, slot;
        b = grp(d.x, s.x, NSB); slot = atomicAdd(&cnt[b], 1);
        stage[slot] = mkrec(d.x, s.x); s2b[slot] = (unsigned short)b;
        b = grp(d.y, s.y, NSB); slot = atomicAdd(&cnt[b], 1);
        stage[slot] = mkrec(d.y, s.y); s2b[slot] = (unsigned short)b;
        b = grp(d.z, s.z, NSB); slot = atomicAdd(&cnt[b], 1);
        stage[slot] = mkrec(d.z, s.z); s2b[slot] = (unsigned short)b;
        b = grp(d.w, s.w, NSB); slot = atomicAdd(&cnt[b], 1);
        stage[slot] = mkrec(d.w, s.w); s2b[slot] = (unsigned short)b;
    }
    for (int k = (n4 << 2) + t; k < end; k += 1024) {
        int d = dst[s0 + k], s = src[s0 + k];
        int b = grp(d, s, NSB);
        int slot = atomicAdd(&cnt[b], 1);
        stage[slot] = mkrec(d, s);
        s2b[slot] = (unsigned short)b;
    }
    __syncthreads();

    // ---- phase D: coalesced flush ----
    for (int i = t; i < end; i += 1024)
        recs[(long)res[s2b[i]] + i] = stage[i];
}

// ---- deg count per dst-window -> dinv, v(fp16) ----
__global__ __launch_bounds__(512) void k_degv(const int* __restrict__ recs,
                                              const int* __restrict__ cntP,
                                              const int* __restrict__ scanoff,
                                              int NSB,
                                              const float* __restrict__ x,
                                              float* __restrict__ dinv,
                                              _Float16* __restrict__ v, int N) {
    __shared__ int c[DW];
    int t = threadIdx.x, w = blockIdx.x;
#pragma unroll
    for (int j = 0; j < DW / 512; ++j) c[t + 512 * j] = 0;
    __syncthreads();
    for (int sb = 0; sb < NSB; ++sb) {
        int g = w * NSB + sb;
        int base = scanoff[g];
        int cnt = cntP[g * CPAD];
        const vint4* p = reinterpret_cast<const vint4*>(recs + base);
        int n4 = cnt >> 2;
        for (int k = t; k < n4; k += 512) {
            vint4 r = __builtin_nontemporal_load(p + k);
            atomicAdd(&c[((unsigned)r.x) >> SSH], 1);
            atomicAdd(&c[((unsigned)r.y) >> SSH], 1);
            atomicAdd(&c[((unsigned)r.z) >> SSH], 1);
            atomicAdd(&c[((unsigned)r.w) >> SSH], 1);
        }
        for (int k = (n4 << 2) + t; k < cnt; k += 512)
            atomicAdd(&c[((unsigned)__builtin_nontemporal_load(recs + base + k)) >> SSH], 1);
    }
    __syncthreads();
#pragma unroll
    for (int j = 0; j < DW / 512; ++j) {
        int idx = t + 512 * j;
        int node = w * DW + idx;
        if (node < N) {
            float di = rsqrtf((float)c[idx] + 1.0f);
            dinv[node] = di;
            v[node] = (_Float16)(di * x[node]);
        }
    }
}

// ---- layer-1: slice-staged gather (LDS) + scatter (LDS) + fused MLP -> u ----
__global__ __launch_bounds__(512) void k_gs1(const int* __restrict__ recs,
                                             const int* __restrict__ cntP,
                                             const int* __restrict__ scanoff,
                                             int NSB,
                                             const _Float16* __restrict__ v,
                                             const float* __restrict__ dinv,
                                             const float* __restrict__ W1,
                                             const float* __restrict__ b1,
                                             const float* __restrict__ W2,
                                             _Float16* __restrict__ u, int N) {
    __shared__ float acc[DW];                    // 16 KB
    __shared__ _Float16 slice[2][SW];            // 2 x 64 KB
    int t = threadIdx.x, w = blockIdx.x;
#pragma unroll
    for (int j = 0; j < DW / 512; ++j) acc[t + 512 * j] = 0.0f;

    const vint4* vp = reinterpret_cast<const vint4*>(v);  // 8 fp16 per vint4
    vint4 st[8];
#pragma unroll
    for (int i = 0; i < 8; ++i) st[i] = vp[i * 512 + t];              // sb=0
#pragma unroll
    for (int i = 0; i < 8; ++i) ((vint4*)slice[0])[i * 512 + t] = st[i];
    int p = 0;
    for (int sb = 0; sb < NSB; ++sb) {
        if (sb + 1 < NSB) {
#pragma unroll
            for (int i = 0; i < 8; ++i)
                st[i] = vp[(sb + 1) * (SW / 8) + i * 512 + t];
        }
        __syncthreads();                          // slice[p] writes visible
        int g = w * NSB + sb;
        int base = scanoff[g];
        int cnt = cntP[g * CPAD];
        const _Float16* sl = slice[p];
        const vint4* rp = reinterpret_cast<const vint4*>(recs + base);
        int n4 = cnt >> 2;
        for (int k = t; k < n4; k += 512) {
            vint4 r = __builtin_nontemporal_load(rp + k);
            float a0 = (float)sl[r.x & (SW - 1)];
            float a1 = (float)sl[r.y & (SW - 1)];
            float a2 = (float)sl[r.z & (SW - 1)];
            float a3 = (float)sl[r.w & (SW - 1)];
            atomicAdd(&acc[((unsigned)r.x) >> SSH], a0);
            atomicAdd(&acc[((unsigned)r.y) >> SSH], a1);
            atomicAdd(&acc[((unsigned)r.z) >> SSH], a2);
            atomicAdd(&acc[((unsigned)r.w) >> SSH], a3);
        }
        for (int k = (n4 << 2) + t; k < cnt; k += 512) {
            int r = __builtin_nontemporal_load(recs + base + k);
            atomicAdd(&acc[((unsigned)r) >> SSH], (float)sl[r & (SW - 1)]);
        }
        if (sb + 1 < NSB) {
#pragma unroll
            for (int i = 0; i < 8; ++i) ((vint4*)slice[p ^ 1])[i * 512 + t] = st[i];
        }
        p ^= 1;
    }
    __syncthreads();
#pragma unroll
    for (int j = 0; j < DW / 512; ++j) {
        int idx = t + 512 * j;
        int node = w * DW + idx;
        if (node < N) {
            float di = dinv[node];
            float at = di * (acc[idx] + (float)v[node]);
            float s = 0.0f;
#pragma unroll
            for (int jj = 0; jj < 8; ++jj)
                s += fmaxf(at * W1[jj] + b1[jj], 0.0f) * W2[jj];
            u[node] = (_Float16)(di * s);
        }
    }
}

// ---- layer-2: same structure, val = u, finalize -> out ----
__global__ __launch_bounds__(512) void k_gs2(const int* __restrict__ recs,
                                             const int* __restrict__ cntP,
                                             const int* __restrict__ scanoff,
                                             int NSB,
                                             const _Float16* __restrict__ uval,
                                             const float* __restrict__ dinv,
                                             const float* __restrict__ b2,
                                             float* __restrict__ out, int N) {
    __shared__ float acc[DW];
    __shared__ _Float16 slice[2][SW];
    int t = threadIdx.x, w = blockIdx.x;
#pragma unroll
    for (int j = 0; j < DW / 512; ++j) acc[t + 512 * j] = 0.0f;

    const vint4* vp = reinterpret_cast<const vint4*>(uval);
    vint4 st[8];
#pragma unroll
    for (int i = 0; i < 8; ++i) st[i] = vp[i * 512 + t];
#pragma unroll
    for (int i = 0; i < 8; ++i) ((vint4*)slice[0])[i * 512 + t] = st[i];
    int p = 0;
    for (int sb = 0; sb < NSB; ++sb) {
        if (sb + 1 < NSB) {
#pragma unroll
            for (int i = 0; i < 8; ++i)
                st[i] = vp[(sb + 1) * (SW / 8) + i * 512 + t];
        }
        __syncthreads();
        int g = w * NSB + sb;
        int base = scanoff[g];
        int cnt = cntP[g * CPAD];
        const _Float16* sl = slice[p];
        const vint4* rp = reinterpret_cast<const vint4*>(recs + base);
        int n4 = cnt >> 2;
        for (int k = t; k < n4; k += 512) {
            vint4 r = __builtin_nontemporal_load(rp + k);
            float a0 = (float)sl[r.x & (SW - 1)];
            float a1 = (float)sl[r.y & (SW - 1)];
            float a2 = (float)sl[r.z & (SW - 1)];
            float a3 = (float)sl[r.w & (SW - 1)];
            atomicAdd(&acc[((unsigned)r.x) >> SSH], a0);
            atomicAdd(&acc[((unsigned)r.y) >> SSH], a1);
            atomicAdd(&acc[((unsigned)r.z) >> SSH], a2);
            atomicAdd(&acc[((unsigned)r.w) >> SSH], a3);
        }
        for (int k = (n4 << 2) + t; k < cnt; k += 512) {
            int r = __builtin_nontemporal_load(recs + base + k);
            atomicAdd(&acc[((unsigned)r) >> SSH], (float)sl[r & (SW - 1)]);
        }
        if (sb + 1 < NSB) {
#pragma unroll
            for (int i = 0; i < 8; ++i) ((vint4*)slice[p ^ 1])[i * 512 + t] = st[i];
        }
        p ^= 1;
    }
    __syncthreads();
#pragma unroll
    for (int j = 0; j < DW / 512; ++j) {
        int idx = t + 512 * j;
        int node = w * DW + idx;
        if (node < N)
            out[node] = dinv[node] * (acc[idx] + (float)uval[node]) + b2[0];
    }
}

extern "C" void kernel_launch(void* const* d_in, const int* in_sizes, int n_in,
                              void* d_out, int out_size, void* d_ws, size_t ws_size,
                              hipStream_t stream) {
    const float* x  = (const float*)d_in[0];
    const int*   ei = (const int*)d_in[1];   // [2, E] int32
    const float* W1 = (const float*)d_in[2];
    const float* b1 = (const float*)d_in[3];
    const float* W2 = (const float*)d_in[4];
    const float* b2 = (const float*)d_in[5];
    float* out = (float*)d_out;

    int N = in_sizes[0];
    int E = in_sizes[1] / 2;
    const int* src = ei;
    const int* dst = ei + E;

    int NBW = (N + DW - 1) >> DSH;       // dst-windows (245 for N=1e6)
    int NSB = (N + SW - 1) >> SSH;       // src-blocks  (31)
    int NG  = NBW * NSB;                 // groups      (7595 <= NGMAX)

    // layout: dinv | v | u | cntP | gcurP | scanoff | recs   (order matters:
    // v-slice staging over-reads past v's end into u, which is allocated)
    char* w = (char*)d_ws;
    float*    dinv    = (float*)w;    w += sizeof(float) * (size_t)N;
    _Float16* v       = (_Float16*)w; w += sizeof(_Float16) * (size_t)N;
    _Float16* u       = (_Float16*)w; w += sizeof(_Float16) * (size_t)N;
    int*      cntP    = (int*)w;      w += sizeof(int) * (size_t)NG * CPAD;
    int*      gcurP   = (int*)w;      w += sizeof(int) * (size_t)NG * CPAD;
    int*      scanoff = (int*)w;      w += sizeof(int) * (size_t)(NG + 4);
    int*      recs    = (int*)w;      // E + 4*NG ints (alignment gaps)

    int nzero = NG * CPAD * 2;           // cntP + gcurP contiguous
    int NHB = (E + HCHUNK - 1) / HCHUNK;
    int NSBLK = (E + SCHUNK - 1) / SCHUNK;

    k_zero<<<(nzero + 255) / 256, 256, 0, stream>>>(cntP, nzero);
    k_hist<<<NHB, 1024, 0, stream>>>(src, dst, E, NSB, NG, cntP);
    k_scan<<<1, 1024, 0, stream>>>(cntP, NG, scanoff);
    k_sort<<<NSBLK, 1024, 0, stream>>>(src, dst, E, NSB, NG, scanoff, gcurP, recs);
    k_degv<<<NBW, 512, 0, stream>>>(recs, cntP, scanoff, NSB, x, dinv, v, N);
    k_gs1 <<<NBW, 512, 0, stream>>>(recs, cntP, scanoff, NSB, v, dinv, W1, b1, W2, u, N);
    k_gs2 <<<NBW, 512, 0, stream>>>(recs, cntP, scanoff, NSB, u, dinv, b2, out, N);
}

// Round 4
// 404.858 us; speedup vs baseline: 1.4856x; 1.4856x over previous
//
#include <hip/hip_runtime.h>
#include <math.h>

// GCN 2-layer (1->8->1), collapsed + factored + hierarchical two-level binning.
//
// Math (verified):
//   deg[d]  = #edges into d; dinv = rsqrt(deg+1)            (self-loop)
//   v[i]    = dinv[i]*x[i]                                  (stored fp16)
//   acc1[d] = sum_e v[src[e]]
//   at[i]   = dinv[i]*(acc1[i] + v[i])
//   u[i]    = dinv[i] * sum_j relu(at[i]*W1[j]+b1[j])*W2[j] (stored fp16)
//   out[d]  = dinv[d]*(acc2[d] + u[d]) + b2,  acc2[d] = sum_e u[src[e]]
//
// Round-17: r16's single-pass (dstwin x srcblk) sort at 7595 groups had 6.5x
// write amplification (263MB writes, 1.6 rec/group/chunk) and 255us. The
// LDS-sliced gather premise stands. Fix: TWO-PASS sort.
//   pass1: coarse counting sort by dst-window (245 buckets of 4096; proven
//          r12 structure; u8 slot-map; CHUNK 12288 -> 67KB LDS, 2 blk/CU).
//          rec1 = (dstoff12 << 20) | src20.
//   pass2: per-window src-block binning (31 buckets of 32768): one block per
//          window; coalesced hist -> exact packed offsets (boff) -> scatter
//          (31 run-frontiers, L2-merged). rec2 = (dstoff12 << 15) | srcoff15.
// gs kernels: per window: acc[4096] f32 + double-buffered 64KB v-slice in
// LDS; per edge: ds_read_u16 + LDS atomicAdd. Zero random global requests.
// Workspace guard: two-pass needs ~91MB (recs1+recs2); if ws_size is smaller,
// fall back to the r2-proven random-gather gs on recs1 (correct, ~292us).

typedef int vint4 __attribute__((ext_vector_type(4)));

#define DSH    12         // dst-window shift (4096 nodes)
#define DW     4096
#define SSH    15         // src-block shift (32768 nodes)
#define SW     32768
#define NWMAX  256        // max dst-windows (N <= 2^20)
#define STHR   1024       // sort1 block size
#define CHUNK  12288      // edges per sort1 block (67KB LDS -> 2 blk/CU)
#define BOFFS  33         // boff stride per window (NSB+1 <= 33)

__global__ void k_zero_gcur(int* __restrict__ gcur, int NW) {
    int i = blockIdx.x * blockDim.x + threadIdx.x;
    if (i < NW) gcur[i] = 0;
}

// ---- pass 1: coarse counting sort by dst-window ----
__global__ __launch_bounds__(STHR) void k_sort1(const int* __restrict__ src,
                                                const int* __restrict__ dst,
                                                int E, int NW, int C,
                                                int* __restrict__ gcur,
                                                int* __restrict__ recs) {
    __shared__ int cnt[NWMAX];             // A: counts; C: cursors
    __shared__ int res[NWMAX];
    __shared__ int part[STHR];
    __shared__ int stage[CHUNK];           // 48 KB
    __shared__ unsigned char s2b[CHUNK];   // 12 KB (window id < 256)

    int t = threadIdx.x;
    if (t < NWMAX) cnt[t] = 0;
    __syncthreads();

    long s0 = (long)blockIdx.x * CHUNK;
    long rem = (long)E - s0;
    int end = (int)(rem < CHUNK ? rem : CHUNK);
    const vint4* pd = reinterpret_cast<const vint4*>(dst + s0);
    const vint4* ps = reinterpret_cast<const vint4*>(src + s0);
    int n4 = end >> 2;

    // phase A: histogram (plain loads keep dst lines in L2 for phase C)
    for (int k = t; k < n4; k += STHR) {
        vint4 d = pd[k];
        atomicAdd(&cnt[((unsigned)d.x) >> DSH], 1);
        atomicAdd(&cnt[((unsigned)d.y) >> DSH], 1);
        atomicAdd(&cnt[((unsigned)d.z) >> DSH], 1);
        atomicAdd(&cnt[((unsigned)d.w) >> DSH], 1);
    }
    for (int k = (n4 << 2) + t; k < end; k += STHR)
        atomicAdd(&cnt[((unsigned)dst[s0 + k]) >> DSH], 1);
    __syncthreads();

    // phase B: block scan (1 window/thread; NW <= STHR) + global reservation
    int c0 = (t < NW) ? cnt[t] : 0;
    part[t] = c0;
    __syncthreads();
    for (int o = 1; o < STHR; o <<= 1) {
        int pv = (t >= o) ? part[t - o] : 0;
        __syncthreads();
        part[t] += pv;
        __syncthreads();
    }
    int base0 = (t > 0) ? part[t - 1] : 0;
    if (t < NW) {
        cnt[t] = base0;                    // cursor for phase C
        int r0 = c0 ? atomicAdd(&gcur[t], c0) : 0;
        res[t] = t * C + r0 - base0;
    }
    __syncthreads();

    // phase C: place records into LDS staging (window-ordered)
    for (int k = t; k < n4; k += STHR) {
        vint4 d = pd[k];
        vint4 s = __builtin_nontemporal_load(ps + k);
        int b, slot;
        b = ((unsigned)d.x) >> DSH; slot = atomicAdd(&cnt[b], 1);
        stage[slot] = ((d.x & (DW - 1)) << 20) | s.x; s2b[slot] = (unsigned char)b;
        b = ((unsigned)d.y) >> DSH; slot = atomicAdd(&cnt[b], 1);
        stage[slot] = ((d.y & (DW - 1)) << 20) | s.y; s2b[slot] = (unsigned char)b;
        b = ((unsigned)d.z) >> DSH; slot = atomicAdd(&cnt[b], 1);
        stage[slot] = ((d.z & (DW - 1)) << 20) | s.z; s2b[slot] = (unsigned char)b;
        b = ((unsigned)d.w) >> DSH; slot = atomicAdd(&cnt[b], 1);
        stage[slot] = ((d.w & (DW - 1)) << 20) | s.w; s2b[slot] = (unsigned char)b;
    }
    for (int k = (n4 << 2) + t; k < end; k += STHR) {
        int d = dst[s0 + k], s = src[s0 + k];
        int b = ((unsigned)d) >> DSH;
        int slot = atomicAdd(&cnt[b], 1);
        stage[slot] = ((d & (DW - 1)) << 20) | s;
        s2b[slot] = (unsigned char)b;
    }
    __syncthreads();

    // phase D: flush; long per-window runs -> L2-merged writes
    for (int i = t; i < end; i += STHR)
        recs[(long)res[s2b[i]] + i] = stage[i];
}

// ---- pass 2: per-window src-block binning (exact, packed) ----
__global__ __launch_bounds__(1024) void k_sort2(const int* __restrict__ recs1,
                                                const int* __restrict__ gcur,
                                                int C, int NSB,
                                                int* __restrict__ recs2,
                                                int* __restrict__ boff) {
    __shared__ int hw[16][32];     // wave-private histograms
    __shared__ int cur[32];
    int t = threadIdx.x, w = blockIdx.x, wid = t >> 6;
    for (int i = t; i < 16 * 32; i += 1024) ((int*)hw)[i] = 0;
    __syncthreads();
    int cnt_w = gcur[w];
    long base = (long)w * C;
    for (int k = t; k < cnt_w; k += 1024) {
        int sb = ((unsigned)(recs1[base + k] & 0xFFFFF)) >> SSH;
        atomicAdd(&hw[wid][sb], 1);
    }
    __syncthreads();
    if (t < 32) {
        int s = 0;
        for (int q = 0; q < 16; ++q) s += hw[q][t];
        hw[0][t] = s;
    }
    __syncthreads();
    if (t == 0) {
        int run = 0;
        for (int sb = 0; sb < NSB; ++sb) {
            cur[sb] = run;
            boff[w * BOFFS + sb] = run;
            run += hw[0][sb];
        }
        boff[w * BOFFS + NSB] = cnt_w;
    }
    __syncthreads();
    for (int k = t; k < cnt_w; k += 1024) {
        int r = recs1[base + k];
        int sb = ((unsigned)(r & 0xFFFFF)) >> SSH;
        int slot = atomicAdd(&cur[sb], 1);
        recs2[base + slot] = (int)((((unsigned)r) >> 20) << SSH) | (r & (SW - 1));
    }
}

// ---- deg count per window (reads recs1, dstoff at >>20) -> dinv, v ----
__global__ __launch_bounds__(512) void k_degv(const int* __restrict__ recs1,
                                              const int* __restrict__ gcur, int C,
                                              const float* __restrict__ x,
                                              float* __restrict__ dinv,
                                              _Float16* __restrict__ v, int N) {
    __shared__ int c[DW];
    int t = threadIdx.x, w = blockIdx.x;
#pragma unroll
    for (int j = 0; j < DW / 512; ++j) c[t + 512 * j] = 0;
    __syncthreads();
    long lo = (long)w * C;
    int cnt_ = gcur[w];
    int n4 = cnt_ >> 2;
    const vint4* p = reinterpret_cast<const vint4*>(recs1 + lo);
    for (int k = t; k < n4; k += 512) {
        vint4 r = __builtin_nontemporal_load(p + k);
        atomicAdd(&c[((unsigned)r.x) >> 20], 1);
        atomicAdd(&c[((unsigned)r.y) >> 20], 1);
        atomicAdd(&c[((unsigned)r.z) >> 20], 1);
        atomicAdd(&c[((unsigned)r.w) >> 20], 1);
    }
    for (int k = (n4 << 2) + t; k < cnt_; k += 512)
        atomicAdd(&c[((unsigned)__builtin_nontemporal_load(recs1 + lo + k)) >> 20], 1);
    __syncthreads();
#pragma unroll
    for (int j = 0; j < DW / 512; ++j) {
        int idx = t + 512 * j;
        int node = w * DW + idx;
        if (node < N) {
            float di = rsqrtf((float)c[idx] + 1.0f);
            dinv[node] = di;
            v[node] = (_Float16)(di * x[node]);
        }
    }
}

// ---- layer-1 (two-pass path): LDS-sliced gather + scatter + fused MLP ----
__global__ __launch_bounds__(512) void k_gs1(const int* __restrict__ recs2,
                                             const int* __restrict__ boff,
                                             int C, int NSB,
                                             const _Float16* __restrict__ v,
                                             const float* __restrict__ dinv,
                                             const float* __restrict__ W1,
                                             const float* __restrict__ b1,
                                             const float* __restrict__ W2,
                                             _Float16* __restrict__ u, int N) {
    __shared__ float acc[DW];                // 16 KB
    __shared__ _Float16 slice[2][SW];        // 2 x 64 KB
    int t = threadIdx.x, w = blockIdx.x;
#pragma unroll
    for (int j = 0; j < DW / 512; ++j) acc[t + 512 * j] = 0.0f;

    const vint4* vp = reinterpret_cast<const vint4*>(v);   // 8 fp16 / 16B
    vint4 st[8];
#pragma unroll
    for (int i = 0; i < 8; ++i) st[i] = vp[i * 512 + t];   // sb = 0
#pragma unroll
    for (int i = 0; i < 8; ++i) ((vint4*)slice[0])[i * 512 + t] = st[i];
    int p = 0;
    long base = (long)w * C;
    for (int sb = 0; sb < NSB; ++sb) {
        if (sb + 1 < NSB) {
#pragma unroll
            for (int i = 0; i < 8; ++i)
                st[i] = vp[(long)(sb + 1) * (SW / 8) + i * 512 + t];
        }
        __syncthreads();                     // slice[p] writes visible
        int k0 = boff[w * BOFFS + sb], k1 = boff[w * BOFFS + sb + 1];
        const _Float16* sl = slice[p];
        for (int k = k0 + t; k < k1; k += 512) {
            int r = recs2[base + k];
            atomicAdd(&acc[((unsigned)r) >> SSH], (float)sl[r & (SW - 1)]);
        }
        if (sb + 1 < NSB) {
#pragma unroll
            for (int i = 0; i < 8; ++i) ((vint4*)slice[p ^ 1])[i * 512 + t] = st[i];
        }
        p ^= 1;
    }
    __syncthreads();
#pragma unroll
    for (int j = 0; j < DW / 512; ++j) {
        int idx = t + 512 * j;
        int node = w * DW + idx;
        if (node < N) {
            float di = dinv[node];
            float at = di * (acc[idx] + (float)v[node]);
            float s = 0.0f;
#pragma unroll
            for (int jj = 0; jj < 8; ++jj)
                s += fmaxf(at * W1[jj] + b1[jj], 0.0f) * W2[jj];
            u[node] = (_Float16)(di * s);
        }
    }
}

// ---- layer-2 (two-pass path): same, val = u, finalize ----
__global__ __launch_bounds__(512) void k_gs2(const int* __restrict__ recs2,
                                             const int* __restrict__ boff,
                                             int C, int NSB,
                                             const _Float16* __restrict__ uval,
                                             const float* __restrict__ dinv,
                                             const float* __restrict__ b2,
                                             float* __restrict__ out, int N) {
    __shared__ float acc[DW];
    __shared__ _Float16 slice[2][SW];
    int t = threadIdx.x, w = blockIdx.x;
#pragma unroll
    for (int j = 0; j < DW / 512; ++j) acc[t + 512 * j] = 0.0f;

    const vint4* vp = reinterpret_cast<const vint4*>(uval);
    vint4 st[8];
#pragma unroll
    for (int i = 0; i < 8; ++i) st[i] = vp[i * 512 + t];
#pragma unroll
    for (int i = 0; i < 8; ++i) ((vint4*)slice[0])[i * 512 + t] = st[i];
    int p = 0;
    long base = (long)w * C;
    for (int sb = 0; sb < NSB; ++sb) {
        if (sb + 1 < NSB) {
#pragma unroll
            for (int i = 0; i < 8; ++i)
                st[i] = vp[(long)(sb + 1) * (SW / 8) + i * 512 + t];
        }
        __syncthreads();
        int k0 = boff[w * BOFFS + sb], k1 = boff[w * BOFFS + sb + 1];
        const _Float16* sl = slice[p];
        for (int k = k0 + t; k < k1; k += 512) {
            int r = recs2[base + k];
            atomicAdd(&acc[((unsigned)r) >> SSH], (float)sl[r & (SW - 1)]);
        }
        if (sb + 1 < NSB) {
#pragma unroll
            for (int i = 0; i < 8; ++i) ((vint4*)slice[p ^ 1])[i * 512 + t] = st[i];
        }
        p ^= 1;
    }
    __syncthreads();
#pragma unroll
    for (int j = 0; j < DW / 512; ++j) {
        int idx = t + 512 * j;
        int node = w * DW + idx;
        if (node < N)
            out[node] = dinv[node] * (acc[idx] + (float)uval[node]) + b2[0];
    }
}

// ---- fallback path (ws too small for recs2): random-gather gs on recs1 ----
__global__ __launch_bounds__(512) void k_gr1(const int* __restrict__ recs1,
                                             const int* __restrict__ gcur, int C,
                                             const _Float16* __restrict__ v,
                                             const float* __restrict__ dinv,
                                             const float* __restrict__ W1,
                                             const float* __restrict__ b1,
                                             const float* __restrict__ W2,
                                             _Float16* __restrict__ u, int N) {
    __shared__ float acc[DW];
    int t = threadIdx.x, w = blockIdx.x;
#pragma unroll
    for (int j = 0; j < DW / 512; ++j) acc[t + 512 * j] = 0.0f;
    __syncthreads();
    long lo = (long)w * C;
    int cnt_ = gcur[w];
    int n4 = cnt_ >> 2;
    const vint4* p = reinterpret_cast<const vint4*>(recs1 + lo);
    for (int k = t; k < n4; k += 512) {
        vint4 r = __builtin_nontemporal_load(p + k);
        float a0 = (float)v[r.x & 0xFFFFF], a1 = (float)v[r.y & 0xFFFFF];
        float a2 = (float)v[r.z & 0xFFFFF], a3 = (float)v[r.w & 0xFFFFF];
        atomicAdd(&acc[((unsigned)r.x) >> 20], a0);
        atomicAdd(&acc[((unsigned)r.y) >> 20], a1);
        atomicAdd(&acc[((unsigned)r.z) >> 20], a2);
        atomicAdd(&acc[((unsigned)r.w) >> 20], a3);
    }
    for (int k = (n4 << 2) + t; k < cnt_; k += 512) {
        int r = __builtin_nontemporal_load(recs1 + lo + k);
        atomicAdd(&acc[((unsigned)r) >> 20], (float)v[r & 0xFFFFF]);
    }
    __syncthreads();
#pragma unroll
    for (int j = 0; j < DW / 512; ++j) {
        int idx = t + 512 * j;
        int node = w * DW + idx;
        if (node < N) {
            float di = dinv[node];
            float at = di * (acc[idx] + (float)v[node]);
            float s = 0.0f;
#pragma unroll
            for (int jj = 0; jj < 8; ++jj)
                s += fmaxf(at * W1[jj] + b1[jj], 0.0f) * W2[jj];
            u[node] = (_Float16)(di * s);
        }
    }
}

__global__ __launch_bounds__(512) void k_gr2(const int* __restrict__ recs1,
                                             const int* __restrict__ gcur, int C,
                                             const _Float16* __restrict__ uval,
                                             const float* __restrict__ dinv,
                                             const float* __restrict__ b2,
                                             float* __restrict__ out, int N) {
    __shared__ float acc[DW];
    int t = threadIdx.x, w = blockIdx.x;
#pragma unroll
    for (int j = 0; j < DW / 512; ++j) acc[t + 512 * j] = 0.0f;
    __syncthreads();
    long lo = (long)w * C;
    int cnt_ = gcur[w];
    int n4 = cnt_ >> 2;
    const vint4* p = reinterpret_cast<const vint4*>(recs1 + lo);
    for (int k = t; k < n4; k += 512) {
        vint4 r = __builtin_nontemporal_load(p + k);
        float a0 = (float)uval[r.x & 0xFFFFF], a1 = (float)uval[r.y & 0xFFFFF];
        float a2 = (float)uval[r.z & 0xFFFFF], a3 = (float)uval[r.w & 0xFFFFF];
        atomicAdd(&acc[((unsigned)r.x) >> 20], a0);
        atomicAdd(&acc[((unsigned)r.y) >> 20], a1);
        atomicAdd(&acc[((unsigned)r.z) >> 20], a2);
        atomicAdd(&acc[((unsigned)r.w) >> 20], a3);
    }
    for (int k = (n4 << 2) + t; k < cnt_; k += 512) {
        int r = __builtin_nontemporal_load(recs1 + lo + k);
        atomicAdd(&acc[((unsigned)r) >> 20], (float)uval[r & 0xFFFFF]);
    }
    __syncthreads();
#pragma unroll
    for (int j = 0; j < DW / 512; ++j) {
        int idx = t + 512 * j;
        int node = w * DW + idx;
        if (node < N)
            out[node] = dinv[node] * (acc[idx] + (float)uval[node]) + b2[0];
    }
}

extern "C" void kernel_launch(void* const* d_in, const int* in_sizes, int n_in,
                              void* d_out, int out_size, void* d_ws, size_t ws_size,
                              hipStream_t stream) {
    const float* x  = (const float*)d_in[0];
    const int*   ei = (const int*)d_in[1];   // [2, E] int32
    const float* W1 = (const float*)d_in[2];
    const float* b1 = (const float*)d_in[3];
    const float* W2 = (const float*)d_in[4];
    const float* b2 = (const float*)d_in[5];
    float* out = (float*)d_out;

    int N = in_sizes[0];
    int E = in_sizes[1] / 2;
    const int* src = ei;
    const int* dst = ei + E;

    int NW  = (N + DW - 1) >> DSH;      // dst-windows (245 for N=1e6)
    int NSB = (N + SW - 1) >> SSH;      // src-blocks  (31)

    // window capacity: avg + 8 sigma (Poisson), rounded to 64
    int avg = E / NW;
    int C = avg + 8 * (int)sqrt((double)avg) + 64;
    C = (C + 63) & ~63;

    size_t fixed = 8ul * (size_t)N                 // dinv(4) + v(2) + u(2)
                 + sizeof(int) * (size_t)NW        // gcur
                 + sizeof(int) * (size_t)NW * BOFFS; // boff
    size_t recsz = sizeof(int) * (size_t)C * NW;
    bool two = (ws_size >= fixed + 2 * recsz);
    if (!two) {
        size_t maxC = (ws_size - fixed) / (sizeof(int) * (size_t)NW);
        if ((size_t)C > maxC) C = (int)(maxC & ~63ul);
        recsz = sizeof(int) * (size_t)C * NW;
    }

    char* w = (char*)d_ws;
    float*    dinv  = (float*)w;    w += sizeof(float) * (size_t)N;
    _Float16* v     = (_Float16*)w; w += sizeof(_Float16) * (size_t)N;
    _Float16* u     = (_Float16*)w; w += sizeof(_Float16) * (size_t)N;
    int*      gcur  = (int*)w;      w += sizeof(int) * (size_t)NW;
    int*      boff  = (int*)w;      w += sizeof(int) * (size_t)NW * BOFFS;
    int*      recs1 = (int*)w;      w += recsz;
    int*      recs2 = (int*)w;      // only if two

    int NBLK = (E + CHUNK - 1) / CHUNK;

    k_zero_gcur<<<(NW + 255) / 256, 256, 0, stream>>>(gcur, NW);
    k_sort1<<<NBLK, STHR, 0, stream>>>(src, dst, E, NW, C, gcur, recs1);
    k_degv<<<NW, 512, 0, stream>>>(recs1, gcur, C, x, dinv, v, N);
    if (two) {
        k_sort2<<<NW, 1024, 0, stream>>>(recs1, gcur, C, NSB, recs2, boff);
        k_gs1<<<NW, 512, 0, stream>>>(recs2, boff, C, NSB, v, dinv, W1, b1, W2, u, N);
        k_gs2<<<NW, 512, 0, stream>>>(recs2, boff, C, NSB, u, dinv, b2, out, N);
    } else {
        k_gr1<<<NW, 512, 0, stream>>>(recs1, gcur, C, v, dinv, W1, b1, W2, u, N);
        k_gr2<<<NW, 512, 0, stream>>>(recs1, gcur, C, u, dinv, b2, out, N);
    }
}